// Round 7
// baseline (24153.571 us; speedup 1.0000x reference)
//
#include <hip/hip_runtime.h>

constexpr int TT = 2048;   // timesteps
constexpr int NB = 128;    // batch
constexpr int NI = 64;     // input size
constexpr int NH = 256;    // hidden
constexpr int NGRP = 128;  // WGs per layer
constexpr int NWG  = 256;
constexpr int NTHR = 512;
constexpr int R0 = 8;      // h0 ring slots
constexpr int R1 = 16;     // h1 ring slots
constexpr int SLOT = (NH / 2) * NB;   // dwords per packed-bf16 h slot

// Sharded monotone counters: 8 cachelines per layer, 16 WGs bump each line.
// Epoch e reached <=> every line >= 16*e. Zero at load; reset at end.
__device__ unsigned g_cA[8 * 32];   // layer-0 publishes
__device__ unsigned g_cB[8 * 32];   // layer-1 publishes
__device__ unsigned g_cnt = 0, g_gen = 0;

__device__ __forceinline__ float sigm(float v) { return 1.0f / (1.0f + __expf(-v)); }
__device__ __forceinline__ float tanhfast(float v) {
    float e = __expf(2.0f * v);
    return 1.0f - 2.0f / (e + 1.0f);
}
__device__ __forceinline__ float asfl(unsigned u) { return __uint_as_float(u); }
__device__ __forceinline__ unsigned f2bf(float f) {   // RNE float->bf16 bits
    unsigned u = __float_as_uint(f);
    return (u + 0x7fffu + ((u >> 16) & 1u)) >> 16;
}

// LLC-coherent (agent-scope relaxed) accessors for cross-WG data.
__device__ __forceinline__ unsigned long long ldq(const unsigned* p) {
    return __hip_atomic_load((const unsigned long long*)p, __ATOMIC_RELAXED,
                             __HIP_MEMORY_SCOPE_AGENT);
}
__device__ __forceinline__ unsigned ldd(const unsigned* p) {
    return __hip_atomic_load(p, __ATOMIC_RELAXED, __HIP_MEMORY_SCOPE_AGENT);
}
__device__ __forceinline__ void std_(unsigned* p, unsigned v) {
    __hip_atomic_store(p, v, __ATOMIC_RELAXED, __HIP_MEMORY_SCOPE_AGENT);
}
__device__ __forceinline__ void bump(unsigned* p) {
    (void)__hip_atomic_fetch_add(p, 1u, __ATOMIC_RELAXED, __HIP_MEMORY_SCOPE_AGENT);
}

// 8 lanes poll the 8 shard lines of one layer; others trivially pass.
__device__ __forceinline__ void pollc(const unsigned* base, unsigned tgt, int lane) {
    for (;;) {
        unsigned v = tgt;
        if (lane < 8) v = ldd(base + lane * 32);
        if (__all((int)(v >= tgt))) return;
        __builtin_amdgcn_s_sleep(1);
    }
}

// Wave 0 polls LLC + relays via LDS word; waves 1-7 sleep-spin on LDS.
__device__ __forceinline__ void wg_wait(const unsigned* shards, unsigned ctgt,
                                        unsigned* go, unsigned gtgt,
                                        int wv, int lane) {
    if (wv == 0) {
        pollc(shards, ctgt, lane);
        if (lane == 0)
            __hip_atomic_store(go, gtgt, __ATOMIC_RELAXED, __HIP_MEMORY_SCOPE_WORKGROUP);
    } else {
        while (__hip_atomic_load(go, __ATOMIC_RELAXED,
                                 __HIP_MEMORY_SCOPE_WORKGROUP) < gtgt)
            __builtin_amdgcn_s_sleep(1);
    }
}

// Counter barrier, ONLY for the end-of-kernel reset protocol.
__device__ __forceinline__ void gridbar(unsigned k, bool last) {
    __syncthreads();
    if (threadIdx.x == 0) {
        __threadfence();
        unsigned a = __hip_atomic_fetch_add(&g_cnt, 1u, __ATOMIC_ACQ_REL,
                                            __HIP_MEMORY_SCOPE_AGENT);
        if (a == k * NWG - 1u) {
            if (last) {
                __hip_atomic_store(&g_cnt, 0u, __ATOMIC_RELAXED, __HIP_MEMORY_SCOPE_AGENT);
                __hip_atomic_store(&g_gen, 0u, __ATOMIC_RELEASE, __HIP_MEMORY_SCOPE_AGENT);
            } else {
                __hip_atomic_store(&g_gen, k, __ATOMIC_RELEASE, __HIP_MEMORY_SCOPE_AGENT);
            }
        } else if (!last) {
            while (__hip_atomic_load(&g_gen, __ATOMIC_RELAXED,
                                     __HIP_MEMORY_SCOPE_AGENT) < k)
                __builtin_amdgcn_s_sleep(1);
        }
        __threadfence();
    }
    __syncthreads();
}

// One FMA block: 8 weight rows (2 j x 4 gates) x one k, two b columns.
#define STEPQ(Q, HA, HB)                                   \
    acc[0]  += w00.Q * (HA); acc[1]  += w00.Q * (HB);      \
    acc[2]  += w01.Q * (HA); acc[3]  += w01.Q * (HB);      \
    acc[4]  += w02.Q * (HA); acc[5]  += w02.Q * (HB);      \
    acc[6]  += w03.Q * (HA); acc[7]  += w03.Q * (HB);      \
    acc[8]  += w10.Q * (HA); acc[9]  += w10.Q * (HB);      \
    acc[10] += w11.Q * (HA); acc[11] += w11.Q * (HB);      \
    acc[12] += w12.Q * (HA); acc[13] += w12.Q * (HB);      \
    acc[14] += w13.Q * (HA); acc[15] += w13.Q * (HB);

#define LOADW(W, K, kk)                                                        \
    float4 w00 = *(const float4*)((W) + (size_t)(0 * NH + j0    ) * (K) + (kk)); \
    float4 w01 = *(const float4*)((W) + (size_t)(1 * NH + j0    ) * (K) + (kk)); \
    float4 w02 = *(const float4*)((W) + (size_t)(2 * NH + j0    ) * (K) + (kk)); \
    float4 w03 = *(const float4*)((W) + (size_t)(3 * NH + j0    ) * (K) + (kk)); \
    float4 w10 = *(const float4*)((W) + (size_t)(0 * NH + j0 + 1) * (K) + (kk)); \
    float4 w11 = *(const float4*)((W) + (size_t)(1 * NH + j0 + 1) * (K) + (kk)); \
    float4 w12 = *(const float4*)((W) + (size_t)(2 * NH + j0 + 1) * (K) + (kk)); \
    float4 w13 = *(const float4*)((W) + (size_t)(3 * NH + j0 + 1) * (K) + (kk));

// Partial dot over a 32-long k slice of bf16 h packed [k/2][b][2] (fully
// unrolled: all 16 ldq issued up-front, one vmcnt drain).
__device__ __forceinline__ void partH32(const float* __restrict__ W, int j0,
                                        int kbase, const unsigned* __restrict__ hd,
                                        int lane, float* acc) {
    const unsigned* hp = hd + (size_t)(kbase >> 1) * NB + (lane << 1);
    #pragma unroll
    for (int i = 0; i < 8; ++i) {
        const int kk = kbase + (i << 2);
        LOADW(W, NH, kk)
        unsigned long long q0 = ldq(hp + (size_t)(2 * i) * NB);
        unsigned long long q1 = ldq(hp + (size_t)(2 * i + 1) * NB);
        unsigned d00 = (unsigned)q0, d01 = (unsigned)(q0 >> 32);
        unsigned d10 = (unsigned)q1, d11 = (unsigned)(q1 >> 32);
        STEPQ(x, asfl(d00 << 16),          asfl(d01 << 16))
        STEPQ(y, asfl(d00 & 0xffff0000u),  asfl(d01 & 0xffff0000u))
        STEPQ(z, asfl(d10 << 16),          asfl(d11 << 16))
        STEPQ(w, asfl(d10 & 0xffff0000u),  asfl(d11 & 0xffff0000u))
    }
}

// Partial dot over an 8-long k slice of x stored [b][k] fp32 (cached loads).
__device__ __forceinline__ void partX8(const float* __restrict__ W, int j0,
                                       int k0, const float* __restrict__ xp,
                                       int lane, float* acc) {
    #pragma unroll
    for (int i4 = 0; i4 < 2; ++i4) {
        const int kk = k0 + (i4 << 2);
        LOADW(W, NI, kk)
        float4 xa = *(const float4*)(xp + (size_t)(lane << 1) * NI + kk);
        float4 xb = *(const float4*)(xp + (size_t)((lane << 1) + 1) * NI + kk);
        STEPQ(x, xa.x, xb.x)
        STEPQ(y, xa.y, xb.y)
        STEPQ(z, xa.z, xb.z)
        STEPQ(w, xa.w, xb.w)
    }
}

__device__ __forceinline__ void writezp(float4* zp, int wv, int lane,
                                        const float* acc) {
    const int b0 = ((wv << 1) + 0) * NB + (lane << 1);
    const int b1 = ((wv << 1) + 1) * NB + (lane << 1);
    zp[b0]     = make_float4(acc[0],  acc[2],  acc[4],  acc[6]);
    zp[b0 + 1] = make_float4(acc[1],  acc[3],  acc[5],  acc[7]);
    zp[b1]     = make_float4(acc[8],  acc[10], acc[12], acc[14]);
    zp[b1 + 1] = make_float4(acc[9],  acc[11], acc[13], acc[15]);
}

// Grid: 256 WGs x 512 thr (1 WG/CU). gid<128: layer 0 (+head), else layer 1.
// WG g owns j0=2g,2g+1 x all 128 b. Per step: CRITICAL phase = Whh·h(t-1)
// over all 8 waves (32 k each) -> zpC; SHADOW phase (previous iteration,
// off the critical path) = Wih·h0 / Wih0·x -> zpS. Combine threads (tid<128)
// add zpC+zpS+bias, apply gates, publish packed-bf16 h; c in registers.
// Ordering proofs: L1 count >= 16(t+2) => L1's shadow(t) done => h0(t) free.
// L0's cross-wait 16(s-5) at shadow(s) covers BOTH the h0-ring overwrite at
// publish h0(s+1) AND head data h1(s-7). L1 shadow(t) needs L0 >= 16(t+3)
// => L0 always >= 1 ahead => h1-ring reads (head lag 7 < R1/2) safe.
__global__ void __launch_bounds__(NTHR, 2) lstm2(
    const float* __restrict__ x,
    const float* __restrict__ h0in, const float* __restrict__ c0in,
    const float* __restrict__ Wih0, const float* __restrict__ Whh0,
    const float* __restrict__ bih0, const float* __restrict__ bhh0,
    const float* __restrict__ Wih1, const float* __restrict__ Whh1,
    const float* __restrict__ bih1, const float* __restrict__ bhh1,
    const float* __restrict__ Wlin, const float* __restrict__ blin,
    float* __restrict__ out,
    unsigned* __restrict__ h0d, unsigned* __restrict__ h1d)
{
    __shared__ __align__(16) float4 zpC[16 * NB];   // critical partials, 32 KB
    __shared__ __align__(16) float4 zpS[16 * NB];   // shadow partials,   32 KB
    __shared__ float red[4];
    __shared__ unsigned goA, goB;

    const int tid  = threadIdx.x;
    const int gid  = blockIdx.x;
    const bool is1 = gid >= NGRP;
    const int g    = is1 ? gid - NGRP : gid;
    const int j0   = g * 2;
    const int lane = tid & 63;
    const int wv   = __builtin_amdgcn_readfirstlane(tid >> 6);

    unsigned* ownS = is1 ? g_cB : g_cA;
    unsigned* crsS = is1 ? g_cA : g_cB;
    unsigned* myline = ownS + (g & 7) * 32;

    // ---- init: biases + c state + h(-1) publish ----
    float4 bsA = make_float4(0, 0, 0, 0), bsB = bsA;
    float cA = 0.f, cB = 0.f;
    if (tid < 128) {
        const float* bi = is1 ? bih1 : bih0;
        const float* bh = is1 ? bhh1 : bhh0;
        bsA.x = bi[0*NH + j0] + bh[0*NH + j0];
        bsA.y = bi[1*NH + j0] + bh[1*NH + j0];
        bsA.z = bi[2*NH + j0] + bh[2*NH + j0];
        bsA.w = bi[3*NH + j0] + bh[3*NH + j0];
        bsB.x = bi[0*NH + j0+1] + bh[0*NH + j0+1];
        bsB.y = bi[1*NH + j0+1] + bh[1*NH + j0+1];
        bsB.z = bi[2*NH + j0+1] + bh[2*NH + j0+1];
        bsB.w = bi[3*NH + j0+1] + bh[3*NH + j0+1];
        const float* cbase = c0in + (is1 ? 1 : 0) * NB * NH + (size_t)tid * NH + j0;
        cA = cbase[0]; cB = cbase[1];
        const float* hbase = h0in + (is1 ? 1 : 0) * NB * NH + (size_t)tid * NH + j0;
        unsigned d = (f2bf(hbase[1]) << 16) | f2bf(hbase[0]);
        unsigned* hT = is1 ? h1d : h0d;
        const int islot = is1 ? (R1 - 1) : (R0 - 1);
        std_(hT + (size_t)islot * SLOT + (size_t)g * NB + tid, d);
    }
    if (tid == 0) { goA = 0; goB = 0; }
    const float blv = blin[0];
    asm volatile("s_waitcnt vmcnt(0)" ::: "memory");
    __syncthreads();
    if (tid == 0) bump(myline);   // each shard line reaches 16 -> epoch 1

    if (!is1) {
        // ================= layer 0 (+ head, lag 7) =================
        {   // prologue shadow(0): Wih0·x(0) -> zpS (no dependency)
            float acc[16] = {0,0,0,0,0,0,0,0,0,0,0,0,0,0,0,0};
            partX8(Wih0, j0, wv * 8, x, lane, acc);
            writezp(zpS, wv, lane, acc);
        }
        for (int s = 0; s < TT + 7; ++s) {
            if (s < TT) {   // critical: wait h0(s-1), compute Whh0 part
                wg_wait(ownS, 16u * (unsigned)(s + 1), &goA, (unsigned)(s + 1), wv, lane);
                float acc[16] = {0,0,0,0,0,0,0,0,0,0,0,0,0,0,0,0};
                partH32(Whh0, j0, wv * 32,
                        h0d + (size_t)((s + R0 - 1) & (R0 - 1)) * SLOT, lane, acc);
                writezp(zpC, wv, lane, acc);
            }
            __syncthreads();
            if (s < TT && tid < 128) {   // combine + publish h0(s)
                float4 zA = bsA, zB = bsB;
                #pragma unroll
                for (int q = 0; q < 8; ++q) {
                    float4 a  = zpC[(q*2+0)*NB + tid];
                    float4 b4 = zpC[(q*2+1)*NB + tid];
                    float4 c4 = zpS[(q*2+0)*NB + tid];
                    float4 d4 = zpS[(q*2+1)*NB + tid];
                    zA.x += a.x + c4.x; zA.y += a.y + c4.y;
                    zA.z += a.z + c4.z; zA.w += a.w + c4.w;
                    zB.x += b4.x + d4.x; zB.y += b4.y + d4.y;
                    zB.z += b4.z + d4.z; zB.w += b4.w + d4.w;
                }
                float iA = sigm(zA.x), fA = sigm(zA.y), gA = tanhfast(zA.z), oA = sigm(zA.w);
                cA = fA * cA + iA * gA;
                float hA = oA * tanhfast(cA);
                float iB = sigm(zB.x), fB = sigm(zB.y), gB = tanhfast(zB.z), oB = sigm(zB.w);
                cB = fB * cB + iB * gB;
                float hB = oB * tanhfast(cB);
                unsigned d = (f2bf(hB) << 16) | f2bf(hA);
                std_(h0d + (size_t)(s & (R0 - 1)) * SLOT + (size_t)g * NB + tid, d);
            }
            asm volatile("s_waitcnt vmcnt(0)" ::: "memory");
            __syncthreads();
            if (s < TT && tid == 0) bump(myline);

            // ---- shadow phase (off critical path): x(s+1) part + head u=s-7 ----
            if (s >= 5)
                wg_wait(crsS, 16u * (unsigned)(s - 5), &goB, (unsigned)(s - 4), wv, lane);
            if (s + 1 < TT) {
                float acc[16] = {0,0,0,0,0,0,0,0,0,0,0,0,0,0,0,0};
                partX8(Wih0, j0, wv * 8, x + (size_t)(s + 1) * NB * NI, lane, acc);
                writezp(zpS, wv, lane, acc);
            }
            if (s >= 7 && tid >= 256) {
                const int u = s - 7;
                const int k = tid - 256;
                unsigned d = ldd(h1d + (size_t)(u & (R1 - 1)) * SLOT
                                 + (size_t)(k >> 1) * NB + g);
                float hv = (k & 1) ? asfl(d & 0xffff0000u) : asfl(d << 16);
                float p = Wlin[k] * hv;
                #pragma unroll
                for (int off = 32; off; off >>= 1) p += __shfl_down(p, off);
                if (lane == 0) red[wv - 4] = p;
            }
            __syncthreads();
            if (s >= 7 && tid == 256)
                out[(size_t)(s - 7) * NB + g] = red[0] + red[1] + red[2] + red[3] + blv;
        }
    } else {
        // ================= layer 1 =================
        // prologue shadow(0): wait h0(0) (epoch 2), compute Wih1·h0(0)
        wg_wait(crsS, 32u, &goB, 1u, wv, lane);
        {
            float acc[16] = {0,0,0,0,0,0,0,0,0,0,0,0,0,0,0,0};
            partH32(Wih1, j0, wv * 32, h0d, lane, acc);
            writezp(zpS, wv, lane, acc);
        }
        for (int t = 0; t < TT; ++t) {
            // critical: wait h1(t-1), compute Whh1 part over all 8 waves
            wg_wait(ownS, 16u * (unsigned)(t + 1), &goA, (unsigned)(t + 1), wv, lane);
            float acc[16] = {0,0,0,0,0,0,0,0,0,0,0,0,0,0,0,0};
            partH32(Whh1, j0, wv * 32,
                    h1d + (size_t)((t + R1 - 1) & (R1 - 1)) * SLOT, lane, acc);
            writezp(zpC, wv, lane, acc);
            __syncthreads();
            if (tid < 128) {   // combine + publish h1(t)
                float4 zA = bsA, zB = bsB;
                #pragma unroll
                for (int q = 0; q < 8; ++q) {
                    float4 a  = zpC[(q*2+0)*NB + tid];
                    float4 b4 = zpC[(q*2+1)*NB + tid];
                    float4 c4 = zpS[(q*2+0)*NB + tid];
                    float4 d4 = zpS[(q*2+1)*NB + tid];
                    zA.x += a.x + c4.x; zA.y += a.y + c4.y;
                    zA.z += a.z + c4.z; zA.w += a.w + c4.w;
                    zB.x += b4.x + d4.x; zB.y += b4.y + d4.y;
                    zB.z += b4.z + d4.z; zB.w += b4.w + d4.w;
                }
                float iA = sigm(zA.x), fA = sigm(zA.y), gA = tanhfast(zA.z), oA = sigm(zA.w);
                cA = fA * cA + iA * gA;
                float hA = oA * tanhfast(cA);
                float iB = sigm(zB.x), fB = sigm(zB.y), gB = tanhfast(zB.z), oB = sigm(zB.w);
                cB = fB * cB + iB * gB;
                float hB = oB * tanhfast(cB);
                unsigned d = (f2bf(hB) << 16) | f2bf(hA);
                std_(h1d + (size_t)(t & (R1 - 1)) * SLOT + (size_t)g * NB + tid, d);
            }
            asm volatile("s_waitcnt vmcnt(0)" ::: "memory");
            __syncthreads();
            if (tid == 0) bump(myline);

            // shadow for t+1: wait h0(t+1) (epoch t+3), compute Wih1 part
            if (t + 1 < TT) {
                wg_wait(crsS, 16u * (unsigned)(t + 3), &goB, (unsigned)(t + 2), wv, lane);
                float acc2[16] = {0,0,0,0,0,0,0,0,0,0,0,0,0,0,0,0};
                partH32(Wih1, j0, wv * 32,
                        h0d + (size_t)((t + 1) & (R0 - 1)) * SLOT, lane, acc2);
                writezp(zpS, wv, lane, acc2);
            }
        }
    }

    // ---- end protocol: reset counters behind a real barrier (replay-safe) ----
    gridbar(1, false);
    if (gid == 0) {
        if (tid < 8)
            __hip_atomic_store(&g_cA[tid * 32], 0u, __ATOMIC_RELAXED,
                               __HIP_MEMORY_SCOPE_AGENT);
        else if (tid < 16)
            __hip_atomic_store(&g_cB[(tid - 8) * 32], 0u, __ATOMIC_RELAXED,
                               __HIP_MEMORY_SCOPE_AGENT);
    }
    gridbar(2, true);
}

extern "C" void kernel_launch(void* const* d_in, const int* in_sizes, int n_in,
                              void* d_out, int out_size, void* d_ws, size_t ws_size,
                              hipStream_t stream)
{
    const float* x    = (const float*)d_in[0];
    const float* h0in = (const float*)d_in[1];
    const float* c0in = (const float*)d_in[2];
    const float* Wih0 = (const float*)d_in[3];
    const float* Whh0 = (const float*)d_in[4];
    const float* bih0 = (const float*)d_in[5];
    const float* bhh0 = (const float*)d_in[6];
    const float* Wih1 = (const float*)d_in[7];
    const float* Whh1 = (const float*)d_in[8];
    const float* bih1 = (const float*)d_in[9];
    const float* bhh1 = (const float*)d_in[10];
    const float* Wlin = (const float*)d_in[11];
    const float* blin = (const float*)d_in[12];
    float* out = (float*)d_out;

    unsigned* h0d = (unsigned*)d_ws;            // [R0][NH/2][NB] packed bf16
    unsigned* h1d = h0d + (size_t)R0 * SLOT;    // [R1][NH/2][NB] packed bf16

    void* args[] = { &x, &h0in, &c0in, &Wih0, &Whh0, &bih0, &bhh0,
                     &Wih1, &Whh1, &bih1, &bhh1, &Wlin, &blin,
                     &out, &h0d, &h1d };
    hipLaunchCooperativeKernel((void*)lstm2, dim3(NWG), dim3(NTHR), args, 0, stream);
}